// Round 1
// 980.368 us; speedup vs baseline: 1.7148x; 1.7148x over previous
//
#include <hip/hip_runtime.h>
#include <math.h>

// ---------------------------------------------------------------------------
// N2V GCN edge model, fp32.
// Pipeline:
//   deg = indeg(dst)+1 ; dinv = 1/sqrt(deg)
//   L1: A = x@W1 ; B = scatter(A*coef) ; B = relu(B + A/deg + b1)
//   L2: A = B@W2 ; B = scatter(A*coef) ; B = relu(B + A/deg + b2)
//   head: per pair (u,v): feat=[u,v,|u-v|,u*v]; z=relu(feat@M1+mb1); out=z@M2+mb2
// ---------------------------------------------------------------------------

__global__ void k_init_deg(float* __restrict__ deg, int n) {
  int i = blockIdx.x * blockDim.x + threadIdx.x;
  if (i < n) deg[i] = 1.0f;  // self-loop
}

__global__ void k_count_deg(const int* __restrict__ dst, float* __restrict__ deg, int e) {
  int i = blockIdx.x * blockDim.x + threadIdx.x;
  if (i < e) atomicAdd(&deg[dst[i]], 1.0f);
}

__global__ void k_finalize_deg(float* __restrict__ deg, int n) {
  int i = blockIdx.x * blockDim.x + threadIdx.x;
  if (i < n) deg[i] = 1.0f / sqrtf(deg[i]);  // store dinv; 1/deg = dinv*dinv
}

// A[node][j] = sum_k x[node][k] * W[k][j]   (K=128, H=64), one wave per node
__global__ void k_matmul_in(const float* __restrict__ x, const float* __restrict__ W,
                            float* __restrict__ out, int n) {
  __shared__ float xs[4][128];
  int warp = threadIdx.x >> 6, lane = threadIdx.x & 63;
  int node = blockIdx.x * 4 + warp;
  if (node < n) {
    const float* xr = x + (size_t)node * 128;
    xs[warp][lane]      = xr[lane];
    xs[warp][64 + lane] = xr[64 + lane];
  }
  __syncthreads();
  if (node >= n) return;
  float acc = 0.f;
#pragma unroll 8
  for (int k = 0; k < 128; ++k) acc += xs[warp][k] * W[k * 64 + lane];
  out[(size_t)node * 64 + lane] = acc;
}

// A[node][j] = sum_k h[node][k] * W[k][j]   (K=64, H=64), one wave per node
__global__ void k_matmul_hid(const float* __restrict__ h, const float* __restrict__ W,
                             float* __restrict__ out, int n) {
  __shared__ float hs[4][64];
  int warp = threadIdx.x >> 6, lane = threadIdx.x & 63;
  int node = blockIdx.x * 4 + warp;
  if (node < n) hs[warp][lane] = h[(size_t)node * 64 + lane];
  __syncthreads();
  if (node >= n) return;
  float acc = 0.f;
#pragma unroll 8
  for (int k = 0; k < 64; ++k) acc += hs[warp][k] * W[k * 64 + lane];
  out[(size_t)node * 64 + lane] = acc;
}

// one wave per edge: agg[dst][j] += hlin[src][j] * dinv[src]*dinv[dst]
__global__ void k_scatter(const float* __restrict__ hlin, const int* __restrict__ src,
                          const int* __restrict__ dst, const float* __restrict__ dinv,
                          float* __restrict__ agg, int e) {
  int t = blockIdx.x * blockDim.x + threadIdx.x;
  int w = t >> 6, lane = t & 63;
  if (w >= e) return;
  int s = src[w], d = dst[w];
  float c = dinv[s] * dinv[d];
  float val = hlin[(size_t)s * 64 + lane] * c;
  atomicAdd(&agg[(size_t)d * 64 + lane], val);
}

// agg = relu(agg + hlin*dinv^2 + bias[j])  (in place)
__global__ void k_node_out(const float* __restrict__ hlin, const float* __restrict__ bias,
                           const float* __restrict__ dinv, float* __restrict__ agg,
                           size_t total) {
  size_t i = (size_t)blockIdx.x * blockDim.x + threadIdx.x;
  if (i >= total) return;
  int node = (int)(i >> 6);
  int j = (int)(i & 63);
  float di = dinv[node];
  float v = agg[i] + hlin[i] * di * di + bias[j];
  agg[i] = v > 0.f ? v : 0.f;
}

// ---------------------------------------------------------------------------
// Edge head, register-blocked GEMM.
// Block = 256 threads = 64 pairs. lane (0..63) = pair within block.
// Wave w (=tid>>6) owns output columns [16w, 16w+16).
// feat@M1 = u@M1[0:64] + v@M1[64:128] + |u-v|@M1[128:192] + (u*v)@M1[192:256]
// M1 addresses are wave-uniform (readfirstlane) -> s_load broadcast, so the
// inner loop is ~93% v_fmac_f32 with an SGPR operand.
// u/v staged in LDS transposed [j][pair]: main-loop reads are lane-consecutive
// (conflict-free), staged writes hit 2 lanes/bank (free).
// ---------------------------------------------------------------------------
__global__ __launch_bounds__(256) void k_edge_head(
    const float* __restrict__ H, const int* __restrict__ ep,
    const float* __restrict__ M1, const float* __restrict__ mb1,
    const float* __restrict__ M2, const float* __restrict__ mb2,
    float* __restrict__ out, int p_total) {
  __shared__ float u_lds[64][64];   // [j][pair]
  __shared__ float v_lds[64][64];   // [j][pair]
  __shared__ float part_lds[4][64];

  const int tid = threadIdx.x;
  const int lane = tid & 63;        // pair within block
  const int quarter = tid >> 6;     // which 16-float chunk of the row to stage
  const int pair0 = blockIdx.x * 64;
  const int gp = pair0 + lane;

  if (gp < p_total) {
    int a = ep[gp];
    int b = ep[p_total + gp];
    const float4* ua = (const float4*)(H + (size_t)a * 64 + quarter * 16);
    const float4* vb = (const float4*)(H + (size_t)b * 64 + quarter * 16);
#pragma unroll
    for (int q = 0; q < 4; ++q) {
      float4 uu = ua[q];
      float4 vv = vb[q];
      int j = quarter * 16 + q * 4;
      u_lds[j + 0][lane] = uu.x; u_lds[j + 1][lane] = uu.y;
      u_lds[j + 2][lane] = uu.z; u_lds[j + 3][lane] = uu.w;
      v_lds[j + 0][lane] = vv.x; v_lds[j + 1][lane] = vv.y;
      v_lds[j + 2][lane] = vv.z; v_lds[j + 3][lane] = vv.w;
    }
  } else {
#pragma unroll
    for (int q = 0; q < 4; ++q) {
      int j = quarter * 16 + q * 4;
      u_lds[j + 0][lane] = 0.f; u_lds[j + 1][lane] = 0.f;
      u_lds[j + 2][lane] = 0.f; u_lds[j + 3][lane] = 0.f;
      v_lds[j + 0][lane] = 0.f; v_lds[j + 1][lane] = 0.f;
      v_lds[j + 2][lane] = 0.f; v_lds[j + 3][lane] = 0.f;
    }
  }
  __syncthreads();

  // Force the column-group index into an SGPR so M1 addresses are provably
  // wave-uniform -> scalar loads.
  const int cg = __builtin_amdgcn_readfirstlane(quarter);
  const float* __restrict__ M1w = M1 + cg * 16;

  float acc[16];
#pragma unroll
  for (int c = 0; c < 16; ++c) acc[c] = 0.f;

  for (int t = 0; t < 64; ++t) {
    float f0 = u_lds[t][lane];
    float f1 = v_lds[t][lane];
    float f2 = fabsf(f0 - f1);
    float f3 = f0 * f1;
    const float* r0 = M1w + t * 64;          // u block, row t
    const float* r1 = M1w + (t + 64) * 64;   // v block
    const float* r2 = M1w + (t + 128) * 64;  // |u-v| block
    const float* r3 = M1w + (t + 192) * 64;  // u*v block
#pragma unroll
    for (int c = 0; c < 16; ++c) acc[c] = fmaf(f0, r0[c], acc[c]);
#pragma unroll
    for (int c = 0; c < 16; ++c) acc[c] = fmaf(f1, r1[c], acc[c]);
#pragma unroll
    for (int c = 0; c < 16; ++c) acc[c] = fmaf(f2, r2[c], acc[c]);
#pragma unroll
    for (int c = 0; c < 16; ++c) acc[c] = fmaf(f3, r3[c], acc[c]);
  }

  // epilogue: z = relu(acc + mb1); partial = z . M2  (over this wave's 16 cols)
  float part = 0.f;
#pragma unroll
  for (int c = 0; c < 16; ++c) {
    float z = acc[c] + mb1[cg * 16 + c];
    z = z > 0.f ? z : 0.f;
    part = fmaf(z, M2[cg * 16 + c], part);
  }
  part_lds[quarter][lane] = part;
  __syncthreads();

  if (quarter == 0 && gp < p_total) {
    out[gp] = part_lds[0][lane] + part_lds[1][lane] + part_lds[2][lane] +
              part_lds[3][lane] + mb2[0];
  }
}

extern "C" void kernel_launch(void* const* d_in, const int* in_sizes, int n_in,
                              void* d_out, int out_size, void* d_ws, size_t ws_size,
                              hipStream_t stream) {
  const float* x   = (const float*)d_in[0];
  const int*   gei = (const int*)d_in[1];
  const int*   ep  = (const int*)d_in[2];
  const float* W1  = (const float*)d_in[3];
  const float* b1  = (const float*)d_in[4];
  const float* W2  = (const float*)d_in[5];
  const float* b2  = (const float*)d_in[6];
  const float* M1  = (const float*)d_in[7];
  const float* mb1 = (const float*)d_in[8];
  const float* M2  = (const float*)d_in[9];
  const float* mb2 = (const float*)d_in[10];
  float* out = (float*)d_out;

  const int N = in_sizes[0] / 128;
  const int E = in_sizes[1] / 2;
  const int P = in_sizes[2] / 2;
  const int* src = gei;
  const int* dst = gei + E;

  char* ws = (char*)d_ws;
  size_t degBytes = (((size_t)N * 4) + 255) & ~(size_t)255;
  size_t hBytes   = (((size_t)N * 64 * 4) + 255) & ~(size_t)255;
  float* dinv = (float*)ws;                       // N (deg then dinv, in place)
  float* A    = (float*)(ws + degBytes);          // N x 64  (hlin)
  float* B    = (float*)(ws + degBytes + hBytes); // N x 64  (agg -> h)

  const int BLK = 256;
  size_t hTotal = (size_t)N * 64;

  // degree / normalization
  k_init_deg<<<(N + BLK - 1) / BLK, BLK, 0, stream>>>(dinv, N);
  k_count_deg<<<(E + BLK - 1) / BLK, BLK, 0, stream>>>(dst, dinv, E);
  k_finalize_deg<<<(N + BLK - 1) / BLK, BLK, 0, stream>>>(dinv, N);

  // layer 1
  k_matmul_in<<<(N + 3) / 4, BLK, 0, stream>>>(x, W1, A, N);
  hipMemsetAsync(B, 0, hTotal * 4, stream);
  k_scatter<<<(int)(((size_t)E * 64 + BLK - 1) / BLK), BLK, 0, stream>>>(A, src, dst, dinv, B, E);
  k_node_out<<<(int)((hTotal + BLK - 1) / BLK), BLK, 0, stream>>>(A, b1, dinv, B, hTotal);

  // layer 2 (B holds h1; A reused for hlin2, then B reused for agg2)
  k_matmul_hid<<<(N + 3) / 4, BLK, 0, stream>>>(B, W2, A, N);
  hipMemsetAsync(B, 0, hTotal * 4, stream);
  k_scatter<<<(int)(((size_t)E * 64 + BLK - 1) / BLK), BLK, 0, stream>>>(A, src, dst, dinv, B, E);
  k_node_out<<<(int)((hTotal + BLK - 1) / BLK), BLK, 0, stream>>>(A, b2, dinv, B, hTotal);

  // edge head: one block per 64 pairs
  k_edge_head<<<(P + 63) / 64, BLK, 0, stream>>>(B, ep, M1, mb1, M2, mb2, out, P);
}

// Round 2
// 719.453 us; speedup vs baseline: 2.3366x; 1.3627x over previous
//
#include <hip/hip_runtime.h>
#include <math.h>

// ---------------------------------------------------------------------------
// N2V GCN edge model, fp32.
// Pipeline:
//   CSR build: cnt = indeg(dst); dinv = rsqrt(cnt+1); rp = exscan(cnt);
//              srcs[] = src ids bucketed by dst
//   L1: A = x@W1 ; B = relu(gatherCSR(A) + A*dinv^2 + b1)
//   L2: A = B@W2 ; B = relu(gatherCSR(A) + A*dinv^2 + b2)
//   head: per pair (u,v): feat=[u,v,|u-v|,u*v]; z=relu(feat@M1+mb1); out=z@M2+mb2
// Scatter-with-76.8M-float-atomics (293 G atomics/s, 300 MB HBM write-through)
// replaced by CSR gather: zero float atomics, writes drop to 25.6 MB/layer.
// ---------------------------------------------------------------------------

__global__ void k_count_int(const int* __restrict__ dst, int* __restrict__ cnt, int e) {
  int i = blockIdx.x * blockDim.x + threadIdx.x;
  if (i < e) atomicAdd(&cnt[dst[i]], 1);
}

__global__ void k_dinv(const int* __restrict__ cnt, float* __restrict__ dinv, int n) {
  int i = blockIdx.x * blockDim.x + threadIdx.x;
  if (i < n) dinv[i] = rsqrtf((float)cnt[i] + 1.0f);  // self-loop included
}

// exclusive scan, stage 1: 1024 elems per block (256 thr x 4), write
// per-element exclusive-within-block prefix + per-block total.
__global__ __launch_bounds__(256) void k_scan_block(const int* __restrict__ cnt,
                                                    int* __restrict__ rp,
                                                    int* __restrict__ bsum, int n) {
  __shared__ int wsum[4];
  int tid = threadIdx.x;
  int lane = tid & 63, w = tid >> 6;
  int idx = blockIdx.x * 1024 + tid * 4;
  int v0 = (idx + 0 < n) ? cnt[idx + 0] : 0;
  int v1 = (idx + 1 < n) ? cnt[idx + 1] : 0;
  int v2 = (idx + 2 < n) ? cnt[idx + 2] : 0;
  int v3 = (idx + 3 < n) ? cnt[idx + 3] : 0;
  int tot = v0 + v1 + v2 + v3;
  // inclusive wave scan of per-thread totals
  int x = tot;
#pragma unroll
  for (int off = 1; off < 64; off <<= 1) {
    int y = __shfl_up(x, off, 64);
    if (lane >= off) x += y;
  }
  if (lane == 63) wsum[w] = x;
  __syncthreads();
  int woff = 0;
  for (int i = 0; i < w; ++i) woff += wsum[i];
  int run = woff + x - tot;  // exclusive-within-block prefix for this thread
  if (idx + 0 < n) rp[idx + 0] = run; run += v0;
  if (idx + 1 < n) rp[idx + 1] = run; run += v1;
  if (idx + 2 < n) rp[idx + 2] = run; run += v2;
  if (idx + 3 < n) rp[idx + 3] = run;
  if (tid == 255) bsum[blockIdx.x] = wsum[0] + wsum[1] + wsum[2] + wsum[3];
}

// stage 2: exclusive scan of block sums (nb <= 128), one wave.
__global__ void k_scan_bsum(int* __restrict__ bsum, int nb) {
  int l = threadIdx.x;  // 64 threads
  int v0 = (l < nb) ? bsum[l] : 0;
  int v1 = (64 + l < nb) ? bsum[64 + l] : 0;
  int i0 = v0;
#pragma unroll
  for (int off = 1; off < 64; off <<= 1) {
    int y = __shfl_up(i0, off, 64);
    if (l >= off) i0 += y;
  }
  int T0 = __shfl(i0, 63, 64);
  int i1 = v1;
#pragma unroll
  for (int off = 1; off < 64; off <<= 1) {
    int y = __shfl_up(i1, off, 64);
    if (l >= off) i1 += y;
  }
  if (l < nb) bsum[l] = i0 - v0;
  if (64 + l < nb) bsum[64 + l] = T0 + i1 - v1;
}

// stage 3: add block offsets; set rp[n] = E.
__global__ void k_scan_add(int* __restrict__ rp, const int* __restrict__ bsum,
                           int n, int e) {
  int i = blockIdx.x * blockDim.x + threadIdx.x;
  if (i < n) rp[i] += bsum[i >> 10];
  if (i == 0) rp[n] = e;
}

// fill CSR buckets: cur[] starts as a copy of rp[].
__global__ void k_fill(const int* __restrict__ src, const int* __restrict__ dst,
                       int* __restrict__ cur, int* __restrict__ srcs, int e) {
  int i = blockIdx.x * blockDim.x + threadIdx.x;
  if (i >= e) return;
  int pos = atomicAdd(&cur[dst[i]], 1);
  srcs[pos] = src[i];
}

// A[node][j] = sum_k x[node][k] * W[k][j]   (K=128, H=64), one wave per node
__global__ void k_matmul_in(const float* __restrict__ x, const float* __restrict__ W,
                            float* __restrict__ out, int n) {
  __shared__ float xs[4][128];
  int warp = threadIdx.x >> 6, lane = threadIdx.x & 63;
  int node = blockIdx.x * 4 + warp;
  if (node < n) {
    const float* xr = x + (size_t)node * 128;
    xs[warp][lane]      = xr[lane];
    xs[warp][64 + lane] = xr[64 + lane];
  }
  __syncthreads();
  if (node >= n) return;
  float acc = 0.f;
#pragma unroll 8
  for (int k = 0; k < 128; ++k) acc += xs[warp][k] * W[k * 64 + lane];
  out[(size_t)node * 64 + lane] = acc;
}

// A[node][j] = sum_k h[node][k] * W[k][j]   (K=64, H=64), one wave per node
__global__ void k_matmul_hid(const float* __restrict__ h, const float* __restrict__ W,
                             float* __restrict__ out, int n) {
  __shared__ float hs[4][64];
  int warp = threadIdx.x >> 6, lane = threadIdx.x & 63;
  int node = blockIdx.x * 4 + warp;
  if (node < n) hs[warp][lane] = h[(size_t)node * 64 + lane];
  __syncthreads();
  if (node >= n) return;
  float acc = 0.f;
#pragma unroll 8
  for (int k = 0; k < 64; ++k) acc += hs[warp][k] * W[k * 64 + lane];
  out[(size_t)node * 64 + lane] = acc;
}

// one wave per node: out[node] = relu( sum_{incoming e} hlin[src_e]*dinv[src_e]*dinv[node]
//                                      + hlin[node]*dinv[node]^2 + bias )
__global__ void k_gather(const float* __restrict__ hlin, const int* __restrict__ rp,
                         const int* __restrict__ srcs, const float* __restrict__ dinv,
                         const float* __restrict__ bias, float* __restrict__ outB,
                         int n) {
  int warp = threadIdx.x >> 6, lane = threadIdx.x & 63;
  int node = blockIdx.x * 4 + warp;
  if (node >= n) return;
  int beg = rp[node], end = rp[node + 1];
  float dn = dinv[node];
  float acc = hlin[(size_t)node * 64 + lane] * dn * dn;  // self loop
  for (int k = beg; k < end; ++k) {
    int s = __builtin_amdgcn_readfirstlane(srcs[k]);
    float c = dinv[s] * dn;
    acc = fmaf(hlin[(size_t)s * 64 + lane], c, acc);
  }
  float v = acc + bias[lane];
  outB[(size_t)node * 64 + lane] = v > 0.f ? v : 0.f;
}

// ---------------------------------------------------------------------------
// Edge head, register-blocked GEMM (see round-0 notes: SGPR-broadcast M1,
// 64 pairs/block, wave owns 16 columns).
// ---------------------------------------------------------------------------
__global__ __launch_bounds__(256) void k_edge_head(
    const float* __restrict__ H, const int* __restrict__ ep,
    const float* __restrict__ M1, const float* __restrict__ mb1,
    const float* __restrict__ M2, const float* __restrict__ mb2,
    float* __restrict__ out, int p_total) {
  __shared__ float u_lds[64][64];   // [j][pair]
  __shared__ float v_lds[64][64];   // [j][pair]
  __shared__ float part_lds[4][64];

  const int tid = threadIdx.x;
  const int lane = tid & 63;        // pair within block
  const int quarter = tid >> 6;     // which 16-float chunk of the row to stage
  const int pair0 = blockIdx.x * 64;
  const int gp = pair0 + lane;

  if (gp < p_total) {
    int a = ep[gp];
    int b = ep[p_total + gp];
    const float4* ua = (const float4*)(H + (size_t)a * 64 + quarter * 16);
    const float4* vb = (const float4*)(H + (size_t)b * 64 + quarter * 16);
#pragma unroll
    for (int q = 0; q < 4; ++q) {
      float4 uu = ua[q];
      float4 vv = vb[q];
      int j = quarter * 16 + q * 4;
      u_lds[j + 0][lane] = uu.x; u_lds[j + 1][lane] = uu.y;
      u_lds[j + 2][lane] = uu.z; u_lds[j + 3][lane] = uu.w;
      v_lds[j + 0][lane] = vv.x; v_lds[j + 1][lane] = vv.y;
      v_lds[j + 2][lane] = vv.z; v_lds[j + 3][lane] = vv.w;
    }
  } else {
#pragma unroll
    for (int q = 0; q < 4; ++q) {
      int j = quarter * 16 + q * 4;
      u_lds[j + 0][lane] = 0.f; u_lds[j + 1][lane] = 0.f;
      u_lds[j + 2][lane] = 0.f; u_lds[j + 3][lane] = 0.f;
      v_lds[j + 0][lane] = 0.f; v_lds[j + 1][lane] = 0.f;
      v_lds[j + 2][lane] = 0.f; v_lds[j + 3][lane] = 0.f;
    }
  }
  __syncthreads();

  const int cg = __builtin_amdgcn_readfirstlane(quarter);
  const float* __restrict__ M1w = M1 + cg * 16;

  float acc[16];
#pragma unroll
  for (int c = 0; c < 16; ++c) acc[c] = 0.f;

  for (int t = 0; t < 64; ++t) {
    float f0 = u_lds[t][lane];
    float f1 = v_lds[t][lane];
    float f2 = fabsf(f0 - f1);
    float f3 = f0 * f1;
    const float* r0 = M1w + t * 64;          // u block, row t
    const float* r1 = M1w + (t + 64) * 64;   // v block
    const float* r2 = M1w + (t + 128) * 64;  // |u-v| block
    const float* r3 = M1w + (t + 192) * 64;  // u*v block
#pragma unroll
    for (int c = 0; c < 16; ++c) acc[c] = fmaf(f0, r0[c], acc[c]);
#pragma unroll
    for (int c = 0; c < 16; ++c) acc[c] = fmaf(f1, r1[c], acc[c]);
#pragma unroll
    for (int c = 0; c < 16; ++c) acc[c] = fmaf(f2, r2[c], acc[c]);
#pragma unroll
    for (int c = 0; c < 16; ++c) acc[c] = fmaf(f3, r3[c], acc[c]);
  }

  float part = 0.f;
#pragma unroll
  for (int c = 0; c < 16; ++c) {
    float z = acc[c] + mb1[cg * 16 + c];
    z = z > 0.f ? z : 0.f;
    part = fmaf(z, M2[cg * 16 + c], part);
  }
  part_lds[quarter][lane] = part;
  __syncthreads();

  if (quarter == 0 && gp < p_total) {
    out[gp] = part_lds[0][lane] + part_lds[1][lane] + part_lds[2][lane] +
              part_lds[3][lane] + mb2[0];
  }
}

extern "C" void kernel_launch(void* const* d_in, const int* in_sizes, int n_in,
                              void* d_out, int out_size, void* d_ws, size_t ws_size,
                              hipStream_t stream) {
  const float* x   = (const float*)d_in[0];
  const int*   gei = (const int*)d_in[1];
  const int*   ep  = (const int*)d_in[2];
  const float* W1  = (const float*)d_in[3];
  const float* b1  = (const float*)d_in[4];
  const float* W2  = (const float*)d_in[5];
  const float* b2  = (const float*)d_in[6];
  const float* M1  = (const float*)d_in[7];
  const float* mb1 = (const float*)d_in[8];
  const float* M2  = (const float*)d_in[9];
  const float* mb2 = (const float*)d_in[10];
  float* out = (float*)d_out;

  const int N = in_sizes[0] / 128;
  const int E = in_sizes[1] / 2;
  const int P = in_sizes[2] / 2;
  const int* src = gei;
  const int* dst = gei + E;

  char* ws = (char*)d_ws;
  auto align256 = [](size_t b) { return (b + 255) & ~(size_t)255; };
  size_t degBytes  = align256((size_t)N * 4);
  size_t hBytes    = align256((size_t)N * 64 * 4);
  size_t cntBytes  = align256((size_t)N * 4);
  size_t rpBytes   = align256((size_t)(N + 1) * 4);
  size_t srcBytes  = align256((size_t)E * 4);

  float* dinv = (float*)ws;                                  // N
  float* A    = (float*)(ws + degBytes);                     // N x 64 (hlin)
  float* B    = (float*)(ws + degBytes + hBytes);            // N x 64 (h out)
  int*   cnt  = (int*)(ws + degBytes + 2 * hBytes);          // N (counts, then cursor)
  int*   rp   = (int*)(ws + degBytes + 2 * hBytes + cntBytes);          // N+1
  int*   srcs = (int*)(ws + degBytes + 2 * hBytes + cntBytes + rpBytes); // E
  int*   bsum = (int*)(ws + degBytes + 2 * hBytes + cntBytes + rpBytes + srcBytes); // 128

  const int BLK = 256;
  const int nb = (N + 1023) / 1024;  // scan blocks; <=128 supported (N<=131072)

  // ---- CSR build + normalization ----
  hipMemsetAsync(cnt, 0, (size_t)N * 4, stream);
  k_count_int<<<(E + BLK - 1) / BLK, BLK, 0, stream>>>(dst, cnt, E);
  k_dinv<<<(N + BLK - 1) / BLK, BLK, 0, stream>>>(cnt, dinv, N);
  k_scan_block<<<nb, BLK, 0, stream>>>(cnt, rp, bsum, N);
  k_scan_bsum<<<1, 64, 0, stream>>>(bsum, nb);
  k_scan_add<<<(N + BLK - 1) / BLK, BLK, 0, stream>>>(rp, bsum, N, E);
  hipMemcpyAsync(cnt, rp, (size_t)N * 4, hipMemcpyDeviceToDevice, stream);  // cursors
  k_fill<<<(E + BLK - 1) / BLK, BLK, 0, stream>>>(src, dst, cnt, srcs, E);

  // ---- layer 1 ----
  k_matmul_in<<<(N + 3) / 4, BLK, 0, stream>>>(x, W1, A, N);
  k_gather<<<(N + 3) / 4, BLK, 0, stream>>>(A, rp, srcs, dinv, b1, B, N);

  // ---- layer 2 ----
  k_matmul_hid<<<(N + 3) / 4, BLK, 0, stream>>>(B, W2, A, N);
  k_gather<<<(N + 3) / 4, BLK, 0, stream>>>(A, rp, srcs, dinv, b2, B, N);

  // ---- edge head: one block per 64 pairs ----
  k_edge_head<<<(P + 63) / 64, BLK, 0, stream>>>(B, ep, M1, mb1, M2, mb2, out, P);
}

// Round 3
// 586.264 us; speedup vs baseline: 2.8675x; 1.2272x over previous
//
#include <hip/hip_runtime.h>
#include <math.h>

// ---------------------------------------------------------------------------
// N2V GCN edge model, fp32.
// Pipeline:
//   CSR build: cnt = indeg(dst); dinv = rsqrt(cnt+1); rp = exscan(cnt);
//              srcs[] = src ids bucketed by dst
//   L1: A = x@W1 ; B = relu(gatherCSR(A) + A*dinv^2 + b1)
//   L2: A = B@W2 ; B = relu(gatherCSR(A) + A*dinv^2 + b2)
//   head: per pair (u,v): feat=[u,v,|u-v|,u*v]; z=relu(feat@M1+mb1); out=z@M2+mb2
// Round-3: head re-tiled 8 waves x 8 cols x 2 pairs/lane (s_load_dwordx8
// bursts -> SGPR room for compiler prefetch); gather 4-way edge-parallel
// (16-lane groups x float4) to cut the serial dependent-load chain 4x.
// ---------------------------------------------------------------------------

__global__ void k_count_int(const int* __restrict__ dst, int* __restrict__ cnt, int e) {
  int i = blockIdx.x * blockDim.x + threadIdx.x;
  if (i < e) atomicAdd(&cnt[dst[i]], 1);
}

__global__ void k_dinv(const int* __restrict__ cnt, float* __restrict__ dinv, int n) {
  int i = blockIdx.x * blockDim.x + threadIdx.x;
  if (i < n) dinv[i] = rsqrtf((float)cnt[i] + 1.0f);  // self-loop included
}

// exclusive scan, stage 1: 1024 elems per block (256 thr x 4).
__global__ __launch_bounds__(256) void k_scan_block(const int* __restrict__ cnt,
                                                    int* __restrict__ rp,
                                                    int* __restrict__ bsum, int n) {
  __shared__ int wsum[4];
  int tid = threadIdx.x;
  int lane = tid & 63, w = tid >> 6;
  int idx = blockIdx.x * 1024 + tid * 4;
  int v0 = (idx + 0 < n) ? cnt[idx + 0] : 0;
  int v1 = (idx + 1 < n) ? cnt[idx + 1] : 0;
  int v2 = (idx + 2 < n) ? cnt[idx + 2] : 0;
  int v3 = (idx + 3 < n) ? cnt[idx + 3] : 0;
  int tot = v0 + v1 + v2 + v3;
  int x = tot;
#pragma unroll
  for (int off = 1; off < 64; off <<= 1) {
    int y = __shfl_up(x, off, 64);
    if (lane >= off) x += y;
  }
  if (lane == 63) wsum[w] = x;
  __syncthreads();
  int woff = 0;
  for (int i = 0; i < w; ++i) woff += wsum[i];
  int run = woff + x - tot;
  if (idx + 0 < n) rp[idx + 0] = run; run += v0;
  if (idx + 1 < n) rp[idx + 1] = run; run += v1;
  if (idx + 2 < n) rp[idx + 2] = run; run += v2;
  if (idx + 3 < n) rp[idx + 3] = run;
  if (tid == 255) bsum[blockIdx.x] = wsum[0] + wsum[1] + wsum[2] + wsum[3];
}

// stage 2: exclusive scan of block sums (nb <= 128), one wave.
__global__ void k_scan_bsum(int* __restrict__ bsum, int nb) {
  int l = threadIdx.x;  // 64 threads
  int v0 = (l < nb) ? bsum[l] : 0;
  int v1 = (64 + l < nb) ? bsum[64 + l] : 0;
  int i0 = v0;
#pragma unroll
  for (int off = 1; off < 64; off <<= 1) {
    int y = __shfl_up(i0, off, 64);
    if (l >= off) i0 += y;
  }
  int T0 = __shfl(i0, 63, 64);
  int i1 = v1;
#pragma unroll
  for (int off = 1; off < 64; off <<= 1) {
    int y = __shfl_up(i1, off, 64);
    if (l >= off) i1 += y;
  }
  if (l < nb) bsum[l] = i0 - v0;
  if (64 + l < nb) bsum[64 + l] = T0 + i1 - v1;
}

// stage 3: add block offsets; set rp[n] = E.
__global__ void k_scan_add(int* __restrict__ rp, const int* __restrict__ bsum,
                           int n, int e) {
  int i = blockIdx.x * blockDim.x + threadIdx.x;
  if (i < n) rp[i] += bsum[i >> 10];
  if (i == 0) rp[n] = e;
}

// fill CSR buckets: cur[] starts as a copy of rp[].
__global__ void k_fill(const int* __restrict__ src, const int* __restrict__ dst,
                       int* __restrict__ cur, int* __restrict__ srcs, int e) {
  int i = blockIdx.x * blockDim.x + threadIdx.x;
  if (i >= e) return;
  int pos = atomicAdd(&cur[dst[i]], 1);
  srcs[pos] = src[i];
}

// A[node][j] = sum_k x[node][k] * W[k][j]   (K=128, H=64), one wave per node
__global__ void k_matmul_in(const float* __restrict__ x, const float* __restrict__ W,
                            float* __restrict__ out, int n) {
  __shared__ float xs[4][128];
  int warp = threadIdx.x >> 6, lane = threadIdx.x & 63;
  int node = blockIdx.x * 4 + warp;
  if (node < n) {
    const float* xr = x + (size_t)node * 128;
    xs[warp][lane]      = xr[lane];
    xs[warp][64 + lane] = xr[64 + lane];
  }
  __syncthreads();
  if (node >= n) return;
  float acc = 0.f;
#pragma unroll 8
  for (int k = 0; k < 128; ++k) acc += xs[warp][k] * W[k * 64 + lane];
  out[(size_t)node * 64 + lane] = acc;
}

// A[node][j] = sum_k h[node][k] * W[k][j]   (K=64, H=64), one wave per node
__global__ void k_matmul_hid(const float* __restrict__ h, const float* __restrict__ W,
                             float* __restrict__ out, int n) {
  __shared__ float hs[4][64];
  int warp = threadIdx.x >> 6, lane = threadIdx.x & 63;
  int node = blockIdx.x * 4 + warp;
  if (node < n) hs[warp][lane] = h[(size_t)node * 64 + lane];
  __syncthreads();
  if (node >= n) return;
  float acc = 0.f;
#pragma unroll 8
  for (int k = 0; k < 64; ++k) acc += hs[warp][k] * W[k * 64 + lane];
  out[(size_t)node * 64 + lane] = acc;
}

// one wave per node, 4 edge-groups of 16 lanes (lane = 16*g + l16).
// group g handles edges beg+g, beg+g+4, ... ; lane covers cols [4*l16, 4*l16+4).
// 4x shorter serial chain (srcs->dinv->row) than one-edge-at-a-time.
__global__ void k_gather(const float* __restrict__ hlin, const int* __restrict__ rp,
                         const int* __restrict__ srcs, const float* __restrict__ dinv,
                         const float* __restrict__ bias, float* __restrict__ outB,
                         int n) {
  int warp = threadIdx.x >> 6, lane = threadIdx.x & 63;
  int node = blockIdx.x * 4 + warp;
  if (node >= n) return;
  int g = lane >> 4, l16 = lane & 15;
  int beg = rp[node], end = rp[node + 1];
  float dn = dinv[node];
  float ax = 0.f, ay = 0.f, az = 0.f, aw = 0.f;
  for (int k = beg + g; k < end; k += 4) {
    int s = srcs[k];
    float c = dinv[s] * dn;
    float4 h = *(const float4*)(hlin + (size_t)s * 64 + l16 * 4);
    ax = fmaf(h.x, c, ax);
    ay = fmaf(h.y, c, ay);
    az = fmaf(h.z, c, az);
    aw = fmaf(h.w, c, aw);
  }
  // reduce the 4 groups (lanes l16, l16+16, l16+32, l16+48)
#pragma unroll
  for (int off = 16; off < 64; off <<= 1) {
    ax += __shfl_xor(ax, off, 64);
    ay += __shfl_xor(ay, off, 64);
    az += __shfl_xor(az, off, 64);
    aw += __shfl_xor(aw, off, 64);
  }
  if (g == 0) {
    float4 hs = *(const float4*)(hlin + (size_t)node * 64 + l16 * 4);
    float4 bb = *(const float4*)(bias + l16 * 4);
    float dd = dn * dn;
    float4 o;
    o.x = ax + hs.x * dd + bb.x;
    o.y = ay + hs.y * dd + bb.y;
    o.z = az + hs.z * dd + bb.z;
    o.w = aw + hs.w * dd + bb.w;
    o.x = o.x > 0.f ? o.x : 0.f;
    o.y = o.y > 0.f ? o.y : 0.f;
    o.z = o.z > 0.f ? o.z : 0.f;
    o.w = o.w > 0.f ? o.w : 0.f;
    *(float4*)(outB + (size_t)node * 64 + l16 * 4) = o;
  }
}

// ---------------------------------------------------------------------------
// Edge head: 512 threads = 8 waves, 128 pairs/block.
// Wave w owns cols [8w, 8w+8); lane owns pairs (2*lane, 2*lane+1).
// M1 rows arrive as 4x s_load_dwordx8 per t (32 SGPRs) -> compiler can
// double-buffer t+1's scalar loads under t's 64 FMAs (was dwordx16 x4 = 64
// SGPRs, no headroom -> full lgkmcnt drain each t, VALUBusy 60%).
// ---------------------------------------------------------------------------
__global__ __launch_bounds__(512) void k_edge_head(
    const float* __restrict__ H, const int* __restrict__ ep,
    const float* __restrict__ M1, const float* __restrict__ mb1,
    const float* __restrict__ M2, const float* __restrict__ mb2,
    float* __restrict__ out, int p_total) {
  __shared__ float u_lds[64][128];   // [j][pair]
  __shared__ float v_lds[64][128];   // [j][pair]
  __shared__ float part_lds[8][128];

  const int tid = threadIdx.x;
  const int pair0 = blockIdx.x * 128;

  // ---- stage: thread (pi, q) loads 16-float chunk q of pair pi's u,v rows
  {
    const int pi = tid & 127;
    const int q  = tid >> 7;  // 0..3
    const int gp = pair0 + pi;
    if (gp < p_total) {
      int a = ep[gp];
      int b = ep[p_total + gp];
      const float4* ua = (const float4*)(H + (size_t)a * 64 + q * 16);
      const float4* vb = (const float4*)(H + (size_t)b * 64 + q * 16);
#pragma unroll
      for (int r = 0; r < 4; ++r) {
        float4 uu = ua[r];
        float4 vv = vb[r];
        int j = q * 16 + r * 4;
        u_lds[j + 0][pi] = uu.x; u_lds[j + 1][pi] = uu.y;
        u_lds[j + 2][pi] = uu.z; u_lds[j + 3][pi] = uu.w;
        v_lds[j + 0][pi] = vv.x; v_lds[j + 1][pi] = vv.y;
        v_lds[j + 2][pi] = vv.z; v_lds[j + 3][pi] = vv.w;
      }
    } else {
#pragma unroll
      for (int r = 0; r < 4; ++r) {
        int j = q * 16 + r * 4;
        u_lds[j + 0][pi] = 0.f; u_lds[j + 1][pi] = 0.f;
        u_lds[j + 2][pi] = 0.f; u_lds[j + 3][pi] = 0.f;
        v_lds[j + 0][pi] = 0.f; v_lds[j + 1][pi] = 0.f;
        v_lds[j + 2][pi] = 0.f; v_lds[j + 3][pi] = 0.f;
      }
    }
  }
  __syncthreads();

  const int lane = tid & 63;
  const int w = tid >> 6;  // 0..7
  const int cg = __builtin_amdgcn_readfirstlane(w);
  const float* __restrict__ M1w = M1 + cg * 8;
  const int p0 = 2 * lane;

  float acc0[8], acc1[8];
#pragma unroll
  for (int c = 0; c < 8; ++c) { acc0[c] = 0.f; acc1[c] = 0.f; }

#pragma unroll 2
  for (int t = 0; t < 64; ++t) {
    float2 uu = *(const float2*)&u_lds[t][p0];
    float2 vv = *(const float2*)&v_lds[t][p0];
    float d0 = fabsf(uu.x - vv.x), m0 = uu.x * vv.x;
    float d1 = fabsf(uu.y - vv.y), m1 = uu.y * vv.y;
    const float* r0 = M1w + t * 64;          // u block, row t
    const float* r1 = M1w + (t + 64) * 64;   // v block
    const float* r2 = M1w + (t + 128) * 64;  // |u-v| block
    const float* r3 = M1w + (t + 192) * 64;  // u*v block
#pragma unroll
    for (int c = 0; c < 8; ++c) {
      float w0 = r0[c], w1 = r1[c], w2 = r2[c], w3 = r3[c];
      acc0[c] = fmaf(uu.x, w0, acc0[c]);
      acc0[c] = fmaf(vv.x, w1, acc0[c]);
      acc0[c] = fmaf(d0,  w2, acc0[c]);
      acc0[c] = fmaf(m0,  w3, acc0[c]);
      acc1[c] = fmaf(uu.y, w0, acc1[c]);
      acc1[c] = fmaf(vv.y, w1, acc1[c]);
      acc1[c] = fmaf(d1,  w2, acc1[c]);
      acc1[c] = fmaf(m1,  w3, acc1[c]);
    }
  }

  // epilogue: z = relu(acc + mb1); partial = z . M2 over this wave's 8 cols
  float part0 = 0.f, part1 = 0.f;
#pragma unroll
  for (int c = 0; c < 8; ++c) {
    float bb = mb1[cg * 8 + c];
    float m2 = M2[cg * 8 + c];
    float z0 = acc0[c] + bb; z0 = z0 > 0.f ? z0 : 0.f;
    float z1 = acc1[c] + bb; z1 = z1 > 0.f ? z1 : 0.f;
    part0 = fmaf(z0, m2, part0);
    part1 = fmaf(z1, m2, part1);
  }
  part_lds[w][p0]     = part0;
  part_lds[w][p0 + 1] = part1;
  __syncthreads();

  if (tid < 128) {
    int gp = pair0 + tid;
    if (gp < p_total) {
      float s = 0.f;
#pragma unroll
      for (int w8 = 0; w8 < 8; ++w8) s += part_lds[w8][tid];
      out[gp] = s + mb2[0];
    }
  }
}

extern "C" void kernel_launch(void* const* d_in, const int* in_sizes, int n_in,
                              void* d_out, int out_size, void* d_ws, size_t ws_size,
                              hipStream_t stream) {
  const float* x   = (const float*)d_in[0];
  const int*   gei = (const int*)d_in[1];
  const int*   ep  = (const int*)d_in[2];
  const float* W1  = (const float*)d_in[3];
  const float* b1  = (const float*)d_in[4];
  const float* W2  = (const float*)d_in[5];
  const float* b2  = (const float*)d_in[6];
  const float* M1  = (const float*)d_in[7];
  const float* mb1 = (const float*)d_in[8];
  const float* M2  = (const float*)d_in[9];
  const float* mb2 = (const float*)d_in[10];
  float* out = (float*)d_out;

  const int N = in_sizes[0] / 128;
  const int E = in_sizes[1] / 2;
  const int P = in_sizes[2] / 2;
  const int* src = gei;
  const int* dst = gei + E;

  char* ws = (char*)d_ws;
  auto align256 = [](size_t b) { return (b + 255) & ~(size_t)255; };
  size_t degBytes  = align256((size_t)N * 4);
  size_t hBytes    = align256((size_t)N * 64 * 4);
  size_t cntBytes  = align256((size_t)N * 4);
  size_t rpBytes   = align256((size_t)(N + 1) * 4);
  size_t srcBytes  = align256((size_t)E * 4);

  float* dinv = (float*)ws;                                  // N
  float* A    = (float*)(ws + degBytes);                     // N x 64 (hlin)
  float* B    = (float*)(ws + degBytes + hBytes);            // N x 64 (h out)
  int*   cnt  = (int*)(ws + degBytes + 2 * hBytes);          // N (counts -> cursors)
  int*   rp   = (int*)(ws + degBytes + 2 * hBytes + cntBytes);            // N+1
  int*   srcs = (int*)(ws + degBytes + 2 * hBytes + cntBytes + rpBytes);  // E
  int*   bsum = (int*)(ws + degBytes + 2 * hBytes + cntBytes + rpBytes + srcBytes); // 128

  const int BLK = 256;
  const int nb = (N + 1023) / 1024;  // scan blocks; <=128 supported (N<=131072)

  // ---- CSR build + normalization ----
  hipMemsetAsync(cnt, 0, (size_t)N * 4, stream);
  k_count_int<<<(E + BLK - 1) / BLK, BLK, 0, stream>>>(dst, cnt, E);
  k_dinv<<<(N + BLK - 1) / BLK, BLK, 0, stream>>>(cnt, dinv, N);
  k_scan_block<<<nb, BLK, 0, stream>>>(cnt, rp, bsum, N);
  k_scan_bsum<<<1, 64, 0, stream>>>(bsum, nb);
  k_scan_add<<<(N + BLK - 1) / BLK, BLK, 0, stream>>>(rp, bsum, N, E);
  hipMemcpyAsync(cnt, rp, (size_t)N * 4, hipMemcpyDeviceToDevice, stream);  // cursors
  k_fill<<<(E + BLK - 1) / BLK, BLK, 0, stream>>>(src, dst, cnt, srcs, E);

  // ---- layer 1 ----
  k_matmul_in<<<(N + 3) / 4, BLK, 0, stream>>>(x, W1, A, N);
  k_gather<<<(N + 3) / 4, BLK, 0, stream>>>(A, rp, srcs, dinv, b1, B, N);

  // ---- layer 2 ----
  k_matmul_hid<<<(N + 3) / 4, BLK, 0, stream>>>(B, W2, A, N);
  k_gather<<<(N + 3) / 4, BLK, 0, stream>>>(A, rp, srcs, dinv, b2, B, N);

  // ---- edge head: 128 pairs per 512-thread block ----
  k_edge_head<<<(P + 127) / 128, 512, 0, stream>>>(B, ep, M1, mb1, M2, mb2, out, P);
}